// Round 1
// baseline (271.933 us; speedup 1.0000x reference)
//
#include <hip/hip_runtime.h>
#include <hip/hip_bf16.h>

// (B,S,U,H,D) = (4,1024,1024,16,64); NTOK = 4096
typedef unsigned short u16;
typedef __attribute__((ext_vector_type(8))) short bf16x8;
typedef __attribute__((ext_vector_type(4))) float f32x4;
constexpr size_t M1 = 1024 * 1024;

static __device__ __forceinline__ float bf2f(u16 u) {
    return __uint_as_float(((unsigned)u) << 16);
}
static __device__ __forceinline__ u16 f2bf(float f) {
    __hip_bfloat16 h = __float2bfloat16(f);   // RTNE
    return *reinterpret_cast<u16*>(&h);
}
static __device__ __forceinline__ void g2lds16(const void* g, void* l) {
    __builtin_amdgcn_global_load_lds(
        (const __attribute__((address_space(1))) unsigned int*)g,
        (__attribute__((address_space(3))) unsigned int*)l, 16, 0, 0);
}
static __device__ __forceinline__ f32x4 mfma16(bf16x8 a, bf16x8 b, f32x4 c) {
    return __builtin_amdgcn_mfma_f32_16x16x32_bf16(a, b, c, 0, 0, 0);
}
static __device__ __forceinline__ bf16x8 ldfrag(const u16* base, int chunk) {
    return *(const bf16x8*)((const char*)base + (size_t)chunk * 16);
}
static __device__ __forceinline__ float fexp2(float x) {
    return __builtin_amdgcn_exp2f(x);
}

// ---------------------------------------------------------------------------
// Dtype sniffer (insurance; inputs measured bf16 -> flag=0).
// ---------------------------------------------------------------------------
__global__ void sniff_kernel(const u16* __restrict__ q, int* __restrict__ flag) {
    const int i = threadIdx.x;   // 64 threads
    const int e = (q[i] >> 7) & 0xFF;
    const unsigned long long m = __ballot(e >= 130);
    if (i == 0) *flag = (__popcll(m) >= 2) ? 1 : 0;
}

// ---------------------------------------------------------------------------
// Fused 4x weight transpose: dst_z[n][k] = bf16(src_z[k][n]), 1024x1024 each.
// ---------------------------------------------------------------------------
struct T4 { const void* src[4]; u16* dst[4]; };

__global__ __launch_bounds__(256) void transpose64(
    T4 ta, const int* __restrict__ flag, int xRaw)
{
    __shared__ u16 Ts[64][72];
    const void* src = ta.src[blockIdx.z];
    u16* dst = ta.dst[blockIdx.z];
    const int tid = threadIdx.x;
    const int r0 = blockIdx.x * 64;
    const int c0 = blockIdx.y * 64;
    const bool f = xRaw && (*flag != 0);
#pragma unroll
    for (int i = 0; i < 4; ++i) {
        const int idx = tid + i * 256;
        const int r = idx >> 4, c4 = (idx & 15) * 4;
        if (f) {
            const float4 v = *(const float4*)((const float*)src + (size_t)(r0 + r) * 1024 + c0 + c4);
            Ts[r][c4 + 0] = f2bf(v.x); Ts[r][c4 + 1] = f2bf(v.y);
            Ts[r][c4 + 2] = f2bf(v.z); Ts[r][c4 + 3] = f2bf(v.w);
        } else {
            const ushort4 v = *(const ushort4*)((const u16*)src + (size_t)(r0 + r) * 1024 + c0 + c4);
            Ts[r][c4 + 0] = v.x; Ts[r][c4 + 1] = v.y;
            Ts[r][c4 + 2] = v.z; Ts[r][c4 + 3] = v.w;
        }
    }
    __syncthreads();
#pragma unroll
    for (int i = 0; i < 4; ++i) {
        const int idx = tid + i * 256;
        const int r = idx >> 4, c4 = (idx & 15) * 4;
        ushort4 o;
        o.x = Ts[c4 + 0][r]; o.y = Ts[c4 + 1][r];
        o.z = Ts[c4 + 2][r]; o.w = Ts[c4 + 3][r];
        *(ushort4*)(dst + (size_t)(c0 + r) * 1024 + r0 + c4) = o;
    }
}

// ---------------------------------------------------------------------------
// MFMA GEMM, R8: BK 32 -> 64. Counters showed the R7 loop was sync-overhead
// bound (MfmaUtil 11%, HBM 10%, all floors ~8x below dur): 32 K-steps of only
// 16 MFMA/wave each, every step paying waitcnt+barrier convoy. Now 16 K-steps
// of 32 MFMA/wave, double-buffered (2 x 32KB LDS, 2 blocks/CU), drain-style
// vmcnt(0) before the barrier (lead-1 prefetch: stage(t+1) issued right after
// the barrier, lands during compute(t) + the co-resident block's compute).
// Staging granularity: 8 rows x 128B contiguous per g2lds (was 16 x 64B).
// Y = X[4096,1024] @ Wt^T + bias, Wt is [n][k] bf16.
// BM=BN=128, BK=64; 4 waves (2x2), wave subtile 64x64.
// Chunk layout ell(r,kc)=(r>>3)*64+kc*8+(r&7): lane-linear staging,
// frag ds_read_b128 2-way bank-aliased (free, m136).
// Epilogue: C tile through swizzled LDS (reuses staging space) -> full-line
// coalesced 16B stores.
// yMode: 0 = bf16 Y[row][col]; 1 = bf16 per-batch V^T; 2 = d_out (flag dtype).
// ---------------------------------------------------------------------------
struct G1 { const void* X; const u16* Wt; const void* Bias; void* Y; int yMode; };
struct G3 { G1 g[3]; };

union GSMem {
    struct { u16 A[2][128 * 64]; u16 B[2][128 * 64]; } st;   // 64 KB staging
    u16 C[128 * 128];                                         // 32 KB epilogue
};

__global__ __launch_bounds__(256) void gemm_mfma(
    G3 args, const int* __restrict__ flag, int xRaw)
{
    __shared__ __align__(16) GSMem sm;
    const G1 g = args.g[blockIdx.z];
    const bool f  = (*flag != 0);
    const bool xf = xRaw && f;
    const int tid = threadIdx.x;
    const int lane = tid & 63, w = tid >> 6;
    const int quad = lane >> 4, l16 = lane & 15;
    const int wm = (w & 1) * 64, wn = (w >> 1) * 64;
    const int rowBase = blockIdx.x * 128, colBase = blockIdx.y * 128;

    const u16* Xp = (const u16*)g.X;
    const float* Xf = (const float*)g.X;

    f32x4 acc[4][4];
#pragma unroll
    for (int i = 0; i < 4; ++i)
#pragma unroll
        for (int j = 0; j < 4; ++j)
            acc[i][j] = f32x4{0.f, 0.f, 0.f, 0.f};

    // slot l (0..1023) <-> (row r, chunk kc): r=((l>>6)<<3)|(l&7), kc=(l>>3)&7.
    // Per g2lds instruction (64 lanes, c,w fixed): 8 rows x 8 chunks = 8 rows
    // of 128B contiguous; LDS dest = uniform base + lane*16 (linear).
    auto stage = [&](int buf, int k0) {
        // B tile: 128 n-rows x 8 chunks = 1024 -> 4/thread
#pragma unroll
        for (int c = 0; c < 4; ++c) {
            const int l = c * 256 + tid;
            const int r  = ((l >> 6) << 3) | (l & 7);
            const int kc = (l >> 3) & 7;
            g2lds16(g.Wt + (size_t)(colBase + r) * 1024 + k0 + kc * 8,
                    (char*)sm.st.B[buf] + (size_t)l * 16);
        }
        // A tile: 128 m-rows x 8 chunks = 1024 -> 4/thread
        if (!xf) {
#pragma unroll
            for (int c = 0; c < 4; ++c) {
                const int l = c * 256 + tid;
                const int r  = ((l >> 6) << 3) | (l & 7);
                const int kc = (l >> 3) & 7;
                g2lds16(Xp + (size_t)(rowBase + r) * 1024 + k0 + kc * 8,
                        (char*)sm.st.A[buf] + (size_t)l * 16);
            }
        } else {
#pragma unroll
            for (int c = 0; c < 4; ++c) {
                const int l = c * 256 + tid;
                const int r  = ((l >> 6) << 3) | (l & 7);
                const int kc = (l >> 3) & 7;
                const float* p = Xf + (size_t)(rowBase + r) * 1024 + k0 + kc * 8;
                const float4 v0 = *(const float4*)p;
                const float4 v1 = *(const float4*)(p + 4);
                int4 v;
                u16* pv = (u16*)&v;
                pv[0] = f2bf(v0.x); pv[1] = f2bf(v0.y); pv[2] = f2bf(v0.z); pv[3] = f2bf(v0.w);
                pv[4] = f2bf(v1.x); pv[5] = f2bf(v1.y); pv[6] = f2bf(v1.z); pv[7] = f2bf(v1.w);
                *(int4*)((char*)sm.st.A[buf] + (size_t)l * 16) = v;
            }
        }
    };

    auto compute = [&](int buf) {
#pragma unroll
        for (int ks = 0; ks < 2; ++ks) {
            bf16x8 a[4], b[4];
#pragma unroll
            for (int i = 0; i < 4; ++i) {
                const int r = wm + i * 16 + l16;
                a[i] = ldfrag(sm.st.A[buf], ((r >> 3) << 6) | ((ks * 4 + quad) << 3) | (r & 7));
            }
#pragma unroll
            for (int j = 0; j < 4; ++j) {
                const int r = wn + j * 16 + l16;
                b[j] = ldfrag(sm.st.B[buf], ((r >> 3) << 6) | ((ks * 4 + quad) << 3) | (r & 7));
            }
#pragma unroll
            for (int i = 0; i < 4; ++i)
#pragma unroll
                for (int j = 0; j < 4; ++j)
                    acc[i][j] = mfma16(a[i], b[j], acc[i][j]);
        }
    };

    stage(0, 0);
    // waitcnt imm (gfx9): vmcnt[3:0] | expcnt<<4 | lgkmcnt<<8.
    // 0x0070 = vmcnt(0), lgkm(0): tile t fully resident AND my ds_reads of the
    // buffer stage(t+1) is about to overwrite are drained before the barrier.
#pragma unroll 1
    for (int t = 0; t < 16; ++t) {
        __builtin_amdgcn_s_waitcnt(0x0070);
        __builtin_amdgcn_s_barrier();   // all waves: tile t resident; t-1 reads done
        if (t + 1 < 16) stage((t + 1) & 1, (t + 1) * 64);
        compute(t & 1);
    }

    // ---- Epilogue. C[m = quad*4+reg][n = lane&15] (verified m89 layout). ----
    const bool yf = (g.yMode == 2) && f;
    if (yf) {
        // fp32-out fallback (rare path): direct scalar stores
#pragma unroll
        for (int j = 0; j < 4; ++j) {
            const int col = colBase + wn + j * 16 + l16;
            const float bv = ((const float*)g.Bias)[col];
#pragma unroll
            for (int i = 0; i < 4; ++i)
#pragma unroll
                for (int reg = 0; reg < 4; ++reg) {
                    const int row = rowBase + wm + i * 16 + quad * 4 + reg;
                    ((float*)g.Y)[(size_t)row * 1024 + col] = acc[i][j][reg] + bv;
                }
        }
        return;
    }

    __syncthreads();   // staging LDS reads done by all waves; reuse as C
    const bool vmode = (g.yMode == 1);
#pragma unroll
    for (int j = 0; j < 4; ++j) {
        const int cl = wn + j * 16 + l16;
        const float bv = f ? ((const float*)g.Bias)[colBase + cl]
                           : bf2f(((const u16*)g.Bias)[colBase + cl]);
#pragma unroll
        for (int i = 0; i < 4; ++i)
#pragma unroll
            for (int reg = 0; reg < 4; ++reg) {
                const int rl = wm + i * 16 + quad * 4 + reg;
                const int R = vmode ? cl : rl;    // LDS-tile row
                const int Cc = vmode ? rl : cl;   // LDS-tile col
                // chunk-XOR swizzle: 16B chunk (Cc>>3) stored at (Cc>>3)^(R&15)
                const int idx = R * 128 + ((((Cc >> 3) ^ (R & 15)) << 3) | (Cc & 7));
                sm.C[idx] = f2bf(acc[i][j][reg] + bv);
            }
    }
    __syncthreads();

    // Copy out: thread -> (row rr, 64-col half); 8x16B per thread, full lines.
    const int rr = tid >> 1, half = tid & 1;
    u16* dst;
    if (vmode) {
        const int bb = rowBase >> 10, s0 = rowBase & 1023;
        dst = (u16*)g.Y + (size_t)bb * M1 + (size_t)(colBase + rr) * 1024 + s0 + half * 64;
    } else {
        dst = (u16*)g.Y + (size_t)(rowBase + rr) * 1024 + colBase + half * 64;
    }
#pragma unroll
    for (int k2 = 0; k2 < 8; ++k2) {
        const int chunk = half * 8 + k2;
        const int4 v = *(const int4*)(sm.C + rr * 128 + ((chunk ^ (rr & 15)) << 3));
        *(int4*)(dst + k2 * 8) = v;
    }
}

// ---------------------------------------------------------------------------
// Flash attention: paired q-tiles (qp, 15-qp) -> uniform 17 kv-tiles/block,
// double-buffered K/V staging. Softmax base-2. ctx written in place over qw
// (own (qtile,h) slice only). R8: s_setprio(1) around MFMA clusters (m191).
// ---------------------------------------------------------------------------
static __device__ __forceinline__ void attn_strip(
    const u16* __restrict__ Ks, const u16* __restrict__ Vs,
    u16* __restrict__ psw, const bf16x8* aq,
    float* m_run, float* l_run, f32x4* O,
    int w, int quad, int l16, bool diag)
{
    f32x4 s[4];
    __builtin_amdgcn_s_setprio(1);
#pragma unroll
    for (int j = 0; j < 4; ++j) {
        const int r = j * 16 + l16;
        const bf16x8 b0 = ldfrag(Ks, ((r >> 3) << 6) | (quad << 3) | (r & 7));
        const bf16x8 b1 = ldfrag(Ks, ((r >> 3) << 6) | ((4 + quad) << 3) | (r & 7));
        f32x4 z = f32x4{0.f, 0.f, 0.f, 0.f};
        z = mfma16(aq[0], b0, z);
        s[j] = mfma16(aq[1], b1, z);
    }
    __builtin_amdgcn_s_setprio(0);

    const float SC2 = 0.125f * 1.44269504089f;   // scale * log2(e)
    const int qrow0 = w * 16 + quad * 4;
#pragma unroll
    for (int j = 0; j < 4; ++j) {
        const int key = j * 16 + l16;
#pragma unroll
        for (int reg = 0; reg < 4; ++reg) {
            float v = s[j][reg] * SC2;
            if (diag && key > qrow0 + reg) v = -1e30f;
            s[j][reg] = v;
        }
    }

    float alpha[4];
#pragma unroll
    for (int reg = 0; reg < 4; ++reg) {
        float mx = fmaxf(fmaxf(s[0][reg], s[1][reg]), fmaxf(s[2][reg], s[3][reg]));
#pragma unroll
        for (int d = 1; d < 16; d <<= 1)
            mx = fmaxf(mx, __shfl_xor(mx, d));
        const float m_new = fmaxf(m_run[reg], mx);
        alpha[reg] = fexp2(m_run[reg] - m_new);
        float sm = 0.f;
#pragma unroll
        for (int j = 0; j < 4; ++j) {
            const float p = fexp2(s[j][reg] - m_new);
            s[j][reg] = p;
            sm += p;
        }
#pragma unroll
        for (int d = 1; d < 16; d <<= 1)
            sm += __shfl_xor(sm, d);
        l_run[reg] = l_run[reg] * alpha[reg] + sm;
        m_run[reg] = m_new;
    }

#pragma unroll
    for (int j = 0; j < 4; ++j)
#pragma unroll
        for (int reg = 0; reg < 4; ++reg)
            psw[(quad * 4 + reg) * 72 + j * 16 + l16] = f2bf(s[j][reg]);

#pragma unroll
    for (int j = 0; j < 4; ++j)
#pragma unroll
        for (int reg = 0; reg < 4; ++reg)
            O[j][reg] *= alpha[reg];

    bf16x8 ap[2];
#pragma unroll
    for (int kt = 0; kt < 2; ++kt)
        ap[kt] = *(const bf16x8*)((const char*)psw + (size_t)l16 * 144 + kt * 64 + quad * 16);
    __builtin_amdgcn_s_setprio(1);
#pragma unroll
    for (int j = 0; j < 4; ++j) {
        const int r = j * 16 + l16;   // d row of V^T
        const bf16x8 b0 = ldfrag(Vs, ((r >> 3) << 6) | (quad << 3) | (r & 7));
        const bf16x8 b1 = ldfrag(Vs, ((r >> 3) << 6) | ((4 + quad) << 3) | (r & 7));
        O[j] = mfma16(ap[0], b0, O[j]);
        O[j] = mfma16(ap[1], b1, O[j]);
    }
    __builtin_amdgcn_s_setprio(0);
}

__global__ __launch_bounds__(256) void attn_mfma(
    u16* __restrict__ qw, const u16* __restrict__ kw, const u16* __restrict__ vt)
{
    __shared__ __align__(16) u16 QA[64 * 64];
    __shared__ __align__(16) u16 QB[64 * 64];
    __shared__ __align__(16) u16 Ks[2][64 * 64];
    __shared__ __align__(16) u16 Vs[2][64 * 64];
    __shared__ __align__(16) u16 Ps[4][16 * 72];

    const int tid = threadIdx.x;
    const int lane = tid & 63, w = tid >> 6;
    const int quad = lane >> 4, l16 = lane & 15;
    const int qp = blockIdx.x, bh = blockIdx.y;
    const int b = bh >> 4, h = bh & 15;
    const int qtA = qp, qtB = 15 - qp;

    const u16* qgA = qw + (size_t)(b * 1024 + qtA * 64) * 1024 + h * 64;
    const u16* qgB = qw + (size_t)(b * 1024 + qtB * 64) * 1024 + h * 64;
    const u16* kg0 = kw + (size_t)(b * 1024) * 1024 + h * 64;
    const u16* vg0 = vt + (size_t)b * M1 + (size_t)(h * 64) * 1024;

    auto stageKV = [&](int buf, int kb) {
#pragma unroll
        for (int c = 0; c < 2; ++c) {
            const int l = c * 256 + tid;
            const int r = ((l >> 6) << 3) | (l & 7);
            const int kc = (l >> 3) & 7;
            g2lds16(kg0 + (size_t)(kb + r) * 1024 + kc * 8, (char*)Ks[buf] + (size_t)l * 16);
            g2lds16(vg0 + (size_t)r * 1024 + kb + kc * 8,   (char*)Vs[buf] + (size_t)l * 16);
        }
    };

#pragma unroll
    for (int c = 0; c < 2; ++c) {
        const int l = c * 256 + tid;
        const int r = ((l >> 6) << 3) | (l & 7);
        const int kc = (l >> 3) & 7;
        g2lds16(qgA + (size_t)r * 1024 + kc * 8, (char*)QA + (size_t)l * 16);
        g2lds16(qgB + (size_t)r * 1024 + kc * 8, (char*)QB + (size_t)l * 16);
    }
    stageKV(0, 0);
    __syncthreads();

    bf16x8 aqA[2], aqB[2];
    {
        const int r = w * 16 + l16;
#pragma unroll
        for (int kt = 0; kt < 2; ++kt) {
            aqA[kt] = ldfrag(QA, ((r >> 3) << 6) | ((kt * 4 + quad) << 3) | (r & 7));
            aqB[kt] = ldfrag(QB, ((r >> 3) << 6) | ((kt * 4 + quad) << 3) | (r & 7));
        }
    }

    f32x4 OA[4], OB[4];
    float mA[4], lA[4], mB[4], lB[4];
#pragma unroll
    for (int j = 0; j < 4; ++j) {
        OA[j] = f32x4{0.f, 0.f, 0.f, 0.f};
        OB[j] = f32x4{0.f, 0.f, 0.f, 0.f};
        mA[j] = -1e30f; lA[j] = 0.f;
        mB[j] = -1e30f; lB[j] = 0.f;
    }
    u16* psw = Ps[w];

    int cur = 0;
    for (int t = 0; t <= qtB; ++t) {
        if (t < qtB) stageKV(cur ^ 1, (t + 1) * 64);   // overlap with compute
        attn_strip(Ks[cur], Vs[cur], psw, aqB, mB, lB, OB, w, quad, l16, t == qtB);
        if (t <= qtA)
            attn_strip(Ks[cur], Vs[cur], psw, aqA, mA, lA, OA, w, quad, l16, t == qtA);
        __syncthreads();   // next buf resident; this buf free
        cur ^= 1;
    }

#pragma unroll
    for (int half = 0; half < 2; ++half) {
        const int qt = half ? qtB : qtA;
        const float* lr = half ? lB : lA;
        const f32x4* O = half ? OB : OA;
        u16* og = qw + (size_t)(b * 1024 + qt * 64 + w * 16 + quad * 4) * 1024 + h * 64;
#pragma unroll
        for (int reg = 0; reg < 4; ++reg) {
            const float inv = 1.f / lr[reg];
#pragma unroll
            for (int j = 0; j < 4; ++j)
                og[(size_t)reg * 1024 + j * 16 + l16] = f2bf(O[j][reg] * inv);
        }
    }
}

// ---------------------------------------------------------------------------
extern "C" void kernel_launch(void* const* d_in, const int* in_sizes, int n_in,
                              void* d_out, int out_size, void* d_ws, size_t ws_size,
                              hipStream_t stream)
{
    const void* query = d_in[0];
    const void* key   = d_in[1];
    const void* value = d_in[2];
    // d_in[3] = mask: exactly tril(ones) -> causal, not read
    const void* Wq = d_in[4];
    const void* bq = d_in[5];
    const void* Wk = d_in[6];
    const void* bk = d_in[7];
    const void* Wv = d_in[8];
    const void* bv = d_in[9];
    const void* Wo = d_in[10];
    const void* bo = d_in[11];

    // ws (u16 units): qw@0(4M1) kw@4 vt@8 wt_o@12 wt_q@13 wt_k@14 wt_v@15
    // flag@16M1. Total 32MB+4 (proven safe R4-R7).
    u16* qw   = (u16*)d_ws;
    u16* kw   = qw + 4 * M1;
    u16* vt   = qw + 8 * M1;
    u16* wt_o = qw + 12 * M1;
    u16* wt_q = qw + 13 * M1;
    u16* wt_k = qw + 14 * M1;
    u16* wt_v = qw + 15 * M1;
    int* flag = (int*)(qw + 16 * M1);

    sniff_kernel<<<1, 64, 0, stream>>>((const u16*)query, flag);

    T4 wT; wT.src[0] = Wq; wT.src[1] = Wk; wT.src[2] = Wv; wT.src[3] = Wo;
    wT.dst[0] = wt_q; wT.dst[1] = wt_k; wT.dst[2] = wt_v; wT.dst[3] = wt_o;
    transpose64<<<dim3(16, 16, 4), 256, 0, stream>>>(wT, flag, 1);

    G3 qkv;
    qkv.g[0] = G1{query, wt_q, bq, qw, 0};
    qkv.g[1] = G1{key,   wt_k, bk, kw, 0};
    qkv.g[2] = G1{value, wt_v, bv, vt, 1};   // V written pre-transposed
    gemm_mfma<<<dim3(32, 8, 3), 256, 0, stream>>>(qkv, flag, 1);

    attn_mfma<<<dim3(8, 64), 256, 0, stream>>>(qw, kw, vt);

    G3 og;
    og.g[0] = G1{qw, wt_o, bo, d_out, 2};
    og.g[1] = og.g[0]; og.g[2] = og.g[0];
    gemm_mfma<<<dim3(32, 8, 1), 256, 0, stream>>>(og, flag, 0);
}

// Round 2
// 251.575 us; speedup vs baseline: 1.0809x; 1.0809x over previous
//
#include <hip/hip_runtime.h>
#include <hip/hip_bf16.h>

// (B,S,U,H,D) = (4,1024,1024,16,64); NTOK = 4096
typedef unsigned short u16;
typedef __attribute__((ext_vector_type(8))) short bf16x8;
typedef __attribute__((ext_vector_type(4))) float f32x4;
constexpr size_t M1 = 1024 * 1024;

static __device__ __forceinline__ float bf2f(u16 u) {
    return __uint_as_float(((unsigned)u) << 16);
}
static __device__ __forceinline__ u16 f2bf(float f) {
    __hip_bfloat16 h = __float2bfloat16(f);   // RTNE
    return *reinterpret_cast<u16*>(&h);
}
static __device__ __forceinline__ void g2lds16(const void* g, void* l) {
    __builtin_amdgcn_global_load_lds(
        (const __attribute__((address_space(1))) unsigned int*)g,
        (__attribute__((address_space(3))) unsigned int*)l, 16, 0, 0);
}
static __device__ __forceinline__ f32x4 mfma16(bf16x8 a, bf16x8 b, f32x4 c) {
    return __builtin_amdgcn_mfma_f32_16x16x32_bf16(a, b, c, 0, 0, 0);
}
static __device__ __forceinline__ bf16x8 ldfrag(const u16* base, int chunk) {
    return *(const bf16x8*)((const char*)base + (size_t)chunk * 16);
}
static __device__ __forceinline__ float fexp2(float x) {
    return __builtin_amdgcn_exp2f(x);
}

// ---------------------------------------------------------------------------
// Dtype sniffer: inputs are fp32 (flag=1 measured: fp32-out epilogue passes).
// ---------------------------------------------------------------------------
__global__ void sniff_kernel(const u16* __restrict__ q, int* __restrict__ flag) {
    const int i = threadIdx.x;   // 64 threads
    const int e = (q[i] >> 7) & 0xFF;
    const unsigned long long m = __ballot(e >= 130);
    if (i == 0) *flag = (__popcll(m) >= 2) ? 1 : 0;
}

// ---------------------------------------------------------------------------
// Fused 4x weight transpose: dst_z[n][k] = bf16(src_z[k][n]), 1024x1024 each.
// ---------------------------------------------------------------------------
struct T4 { const void* src[4]; u16* dst[4]; };

__global__ __launch_bounds__(256) void transpose64(
    T4 ta, const int* __restrict__ flag, int xRaw)
{
    __shared__ u16 Ts[64][72];
    const void* src = ta.src[blockIdx.z];
    u16* dst = ta.dst[blockIdx.z];
    const int tid = threadIdx.x;
    const int r0 = blockIdx.x * 64;
    const int c0 = blockIdx.y * 64;
    const bool f = xRaw && (*flag != 0);
#pragma unroll
    for (int i = 0; i < 4; ++i) {
        const int idx = tid + i * 256;
        const int r = idx >> 4, c4 = (idx & 15) * 4;
        if (f) {
            const float4 v = *(const float4*)((const float*)src + (size_t)(r0 + r) * 1024 + c0 + c4);
            Ts[r][c4 + 0] = f2bf(v.x); Ts[r][c4 + 1] = f2bf(v.y);
            Ts[r][c4 + 2] = f2bf(v.z); Ts[r][c4 + 3] = f2bf(v.w);
        } else {
            const ushort4 v = *(const ushort4*)((const u16*)src + (size_t)(r0 + r) * 1024 + c0 + c4);
            Ts[r][c4 + 0] = v.x; Ts[r][c4 + 1] = v.y;
            Ts[r][c4 + 2] = v.z; Ts[r][c4 + 3] = v.w;
        }
    }
    __syncthreads();
#pragma unroll
    for (int i = 0; i < 4; ++i) {
        const int idx = tid + i * 256;
        const int r = idx >> 4, c4 = (idx & 15) * 4;
        ushort4 o;
        o.x = Ts[c4 + 0][r]; o.y = Ts[c4 + 1][r];
        o.z = Ts[c4 + 2][r]; o.w = Ts[c4 + 3][r];
        *(ushort4*)(dst + (size_t)(c0 + r) * 1024 + r0 + c4) = o;
    }
}

struct G1 { const void* X; const u16* Wt; const void* Bias; void* Y; int yMode; };
struct G3 { G1 g[3]; };

// ---------------------------------------------------------------------------
// NEW (R9): 256x256-tile GEMM for QKV. R7/R8 counters showed the 128-tile
// 2-phase loop is structurally stalled (MFMA 11%, HBM 10%, VALU 12% -> ~85%
// of each K-step is stage+vmcnt+barrier critical path, m233's signature).
// Fix per m248 (grouped GEMM, K=1024, same shape class): 256^2 tile, 8 waves
// (2M x 4N, per-wave 128x64 out), BK=64 -> 64 MFMA/wave/K-step, double-
// buffered 128 KB LDS, ONE barrier per K-step; stage(t+1) issued before
// compute(t) so loads fly under a ~2500-cycle MFMA window.
// Chunk layout ell(r,kc)=(r>>3)*64+kc*8+(r&7): lane-linear g2lds staging,
// frag ds_read_b128 2-way bank-aliased only (free, m136).
// Grid: (M/256, N/256, z) = (16,4,3) = 192 blocks, single round.
// yMode: 0 = bf16 Y[row][col]; 1 = bf16 per-batch V^T.
// ---------------------------------------------------------------------------
union GS2 {
    struct { u16 A[2][256 * 64]; u16 B[2][256 * 64]; } st;   // 128 KB staging
    u16 C[256 * 256];                                         // 128 KB epilogue
};

__global__ __launch_bounds__(512, 2) void gemm_mfma256(
    G3 args, const int* __restrict__ flag, int xRaw)
{
    __shared__ __align__(16) GS2 sm;
    const G1 g = args.g[blockIdx.z];
    const bool f  = (*flag != 0);
    const bool xf = xRaw && f;
    const int tid = threadIdx.x;
    const int lane = tid & 63, w = tid >> 6;
    const int quad = lane >> 4, l16 = lane & 15;
    const int wr = w >> 2, wc = w & 3;            // 2 x 4 wave grid
    const int rowBase = blockIdx.x * 256, colBase = blockIdx.y * 256;

    const u16* Xp = (const u16*)g.X;
    const float* Xf = (const float*)g.X;

    f32x4 acc[8][4];
#pragma unroll
    for (int i = 0; i < 8; ++i)
#pragma unroll
        for (int j = 0; j < 4; ++j)
            acc[i][j] = f32x4{0.f, 0.f, 0.f, 0.f};

    // slot l (0..2047) <-> (row r, chunk kc): r=((l>>6)<<3)|(l&7), kc=(l>>3)&7.
    auto stage = [&](int buf, int k0) {
        // B tile: 256 n-rows x 8 chunks = 2048 slots -> 4/thread
#pragma unroll
        for (int c = 0; c < 4; ++c) {
            const int l = c * 512 + tid;
            const int r  = ((l >> 6) << 3) | (l & 7);
            const int kc = (l >> 3) & 7;
            g2lds16(g.Wt + (size_t)(colBase + r) * 1024 + k0 + kc * 8,
                    (char*)sm.st.B[buf] + (size_t)l * 16);
        }
        // A tile: 256 m-rows x 8 chunks = 2048 slots -> 4/thread
        if (!xf) {
#pragma unroll
            for (int c = 0; c < 4; ++c) {
                const int l = c * 512 + tid;
                const int r  = ((l >> 6) << 3) | (l & 7);
                const int kc = (l >> 3) & 7;
                g2lds16(Xp + (size_t)(rowBase + r) * 1024 + k0 + kc * 8,
                        (char*)sm.st.A[buf] + (size_t)l * 16);
            }
        } else {
#pragma unroll
            for (int c = 0; c < 4; ++c) {
                const int l = c * 512 + tid;
                const int r  = ((l >> 6) << 3) | (l & 7);
                const int kc = (l >> 3) & 7;
                const float* p = Xf + (size_t)(rowBase + r) * 1024 + k0 + kc * 8;
                const float4 v0 = *(const float4*)p;
                const float4 v1 = *(const float4*)(p + 4);
                int4 v;
                u16* pv = (u16*)&v;
                pv[0] = f2bf(v0.x); pv[1] = f2bf(v0.y); pv[2] = f2bf(v0.z); pv[3] = f2bf(v0.w);
                pv[4] = f2bf(v1.x); pv[5] = f2bf(v1.y); pv[6] = f2bf(v1.z); pv[7] = f2bf(v1.w);
                *(int4*)((char*)sm.st.A[buf] + (size_t)l * 16) = v;
            }
        }
    };

    auto compute = [&](int buf) {
#pragma unroll
        for (int ks = 0; ks < 2; ++ks) {
            bf16x8 b[4];
#pragma unroll
            for (int j = 0; j < 4; ++j) {
                const int r = wc * 64 + j * 16 + l16;
                b[j] = ldfrag(sm.st.B[buf], ((r >> 3) << 6) | ((ks * 4 + quad) << 3) | (r & 7));
            }
#pragma unroll
            for (int i = 0; i < 8; ++i) {
                const int r = wr * 128 + i * 16 + l16;
                const bf16x8 a = ldfrag(sm.st.A[buf], ((r >> 3) << 6) | ((ks * 4 + quad) << 3) | (r & 7));
#pragma unroll
                for (int j = 0; j < 4; ++j)
                    acc[i][j] = mfma16(a, b[j], acc[i][j]);
            }
        }
    };

    stage(0, 0);
    __builtin_amdgcn_s_waitcnt(0x0070);   // vmcnt(0) lgkm(0): tile 0 resident
    __builtin_amdgcn_s_barrier();
#pragma unroll 1
    for (int t = 0; t < 16; ++t) {
        if (t + 1 < 16) stage((t + 1) & 1, (t + 1) * 64);  // issue loads FIRST
        compute(t & 1);                                     // MFMA hides them
        __builtin_amdgcn_s_waitcnt(0x0070);                 // t+1 resident
        __builtin_amdgcn_s_barrier();                       // buf t free
    }

    // ---- Epilogue through swizzled LDS (C layout m89: row=quad*4+reg). ----
    const bool vmode = (g.yMode == 1);
#pragma unroll
    for (int j = 0; j < 4; ++j) {
        const int cl = wc * 64 + j * 16 + l16;
        const float bv = f ? ((const float*)g.Bias)[colBase + cl]
                           : bf2f(((const u16*)g.Bias)[colBase + cl]);
#pragma unroll
        for (int i = 0; i < 8; ++i)
#pragma unroll
            for (int reg = 0; reg < 4; ++reg) {
                const int rl = wr * 128 + i * 16 + quad * 4 + reg;
                const int R = vmode ? cl : rl;    // LDS-tile row
                const int Cc = vmode ? rl : cl;   // LDS-tile col
                // 16B chunk (Cc>>3) stored at (Cc>>3)^(R&31) within the row
                const int idx = R * 256 + ((((Cc >> 3) ^ (R & 31)) << 3) | (Cc & 7));
                sm.C[idx] = f2bf(acc[i][j][reg] + bv);
            }
    }
    __syncthreads();

    // Copy out: thread -> (row rr, 128-col half); 16x16B per thread.
    const int rr = tid >> 1, half = tid & 1;
    u16* dst;
    if (vmode) {
        const int bb = rowBase >> 10, s0 = rowBase & 1023;
        dst = (u16*)g.Y + (size_t)bb * M1 + (size_t)(colBase + rr) * 1024 + s0 + half * 128;
    } else {
        dst = (u16*)g.Y + (size_t)(rowBase + rr) * 1024 + colBase + half * 128;
    }
#pragma unroll
    for (int k2 = 0; k2 < 16; ++k2) {
        const int chunk = half * 16 + k2;
        const int4 v = *(const int4*)(sm.C + rr * 256 + ((chunk ^ (rr & 31)) << 3));
        *(int4*)(dst + k2 * 8) = v;
    }
}

// ---------------------------------------------------------------------------
// Out-projection GEMM: exact R7 kernel (BK=32, triple-buffered, vmcnt(4)).
// 256 blocks, fp32-out path (yMode=2, flag=1).
// ---------------------------------------------------------------------------
union GSMem {
    struct { u16 A[3][128 * 32]; u16 B[3][128 * 32]; } st;   // 48 KB staging
    u16 C[128 * 128];                                         // 32 KB epilogue
};

__global__ __launch_bounds__(256) void gemm_mfma(
    G3 args, const int* __restrict__ flag, int xRaw)
{
    __shared__ __align__(16) GSMem sm;
    const G1 g = args.g[blockIdx.z];
    const bool f  = (*flag != 0);
    const bool xf = xRaw && f;
    const int tid = threadIdx.x;
    const int lane = tid & 63, w = tid >> 6;
    const int quad = lane >> 4, l16 = lane & 15;
    const int wm = (w & 1) * 64, wn = (w >> 1) * 64;
    const int rowBase = blockIdx.x * 128, colBase = blockIdx.y * 128;

    const u16* Xp = (const u16*)g.X;
    const float* Xf = (const float*)g.X;

    f32x4 acc[4][4];
#pragma unroll
    for (int i = 0; i < 4; ++i)
#pragma unroll
        for (int j = 0; j < 4; ++j)
            acc[i][j] = f32x4{0.f, 0.f, 0.f, 0.f};

    auto stage = [&](int buf, int k0) {
#pragma unroll
        for (int c = 0; c < 2; ++c) {
            const int l = c * 256 + tid;
            const int r = ((l >> 5) << 3) | (l & 7);
            const int kc = (l >> 3) & 3;
            g2lds16(g.Wt + (size_t)(colBase + r) * 1024 + k0 + kc * 8,
                    (char*)sm.st.B[buf] + (size_t)l * 16);
        }
        if (!xf) {
#pragma unroll
            for (int c = 0; c < 2; ++c) {
                const int l = c * 256 + tid;
                const int r = ((l >> 5) << 3) | (l & 7);
                const int kc = (l >> 3) & 3;
                g2lds16(Xp + (size_t)(rowBase + r) * 1024 + k0 + kc * 8,
                        (char*)sm.st.A[buf] + (size_t)l * 16);
            }
        } else {
#pragma unroll
            for (int c = 0; c < 2; ++c) {
                const int l = c * 256 + tid;
                const int r = ((l >> 5) << 3) | (l & 7);
                const int kc = (l >> 3) & 3;
                const float* p = Xf + (size_t)(rowBase + r) * 1024 + k0 + kc * 8;
                const float4 v0 = *(const float4*)p;
                const float4 v1 = *(const float4*)(p + 4);
                int4 v;
                u16* pv = (u16*)&v;
                pv[0] = f2bf(v0.x); pv[1] = f2bf(v0.y); pv[2] = f2bf(v0.z); pv[3] = f2bf(v0.w);
                pv[4] = f2bf(v1.x); pv[5] = f2bf(v1.y); pv[6] = f2bf(v1.z); pv[7] = f2bf(v1.w);
                *(int4*)((char*)sm.st.A[buf] + (size_t)l * 16) = v;
            }
        }
    };

    auto compute = [&](int buf) {
        bf16x8 a[4], b[4];
#pragma unroll
        for (int i = 0; i < 4; ++i) {
            const int r = wm + i * 16 + l16;
            a[i] = ldfrag(sm.st.A[buf], ((r >> 3) << 5) | (quad << 3) | (r & 7));
        }
#pragma unroll
        for (int j = 0; j < 4; ++j) {
            const int r = wn + j * 16 + l16;
            b[j] = ldfrag(sm.st.B[buf], ((r >> 3) << 5) | (quad << 3) | (r & 7));
        }
#pragma unroll
        for (int i = 0; i < 4; ++i)
#pragma unroll
            for (int j = 0; j < 4; ++j)
                acc[i][j] = mfma16(a[i], b[j], acc[i][j]);
    };

    stage(0, 0);
    stage(1, 32);
    // 0x0074 = vmcnt(4), lgkm(0): tile-t loads done, tile t+1's 4 stay in flight
#pragma unroll 1
    for (int t = 0; t < 31; ++t) {
        __builtin_amdgcn_s_waitcnt(0x0074);
        __builtin_amdgcn_s_barrier();
        if (t + 2 < 32) stage((t + 2) % 3, (t + 2) * 32);
        compute(t % 3);
    }
    __builtin_amdgcn_s_waitcnt(0x0070);
    __builtin_amdgcn_s_barrier();
    compute(31 % 3);

    const bool yf = (g.yMode == 2) && f;
    if (yf) {
#pragma unroll
        for (int j = 0; j < 4; ++j) {
            const int col = colBase + wn + j * 16 + l16;
            const float bv = ((const float*)g.Bias)[col];
#pragma unroll
            for (int i = 0; i < 4; ++i)
#pragma unroll
                for (int reg = 0; reg < 4; ++reg) {
                    const int row = rowBase + wm + i * 16 + quad * 4 + reg;
                    ((float*)g.Y)[(size_t)row * 1024 + col] = acc[i][j][reg] + bv;
                }
        }
        return;
    }

    __syncthreads();
    const bool vmode = (g.yMode == 1);
#pragma unroll
    for (int j = 0; j < 4; ++j) {
        const int cl = wn + j * 16 + l16;
        const float bv = f ? ((const float*)g.Bias)[colBase + cl]
                           : bf2f(((const u16*)g.Bias)[colBase + cl]);
#pragma unroll
        for (int i = 0; i < 4; ++i)
#pragma unroll
            for (int reg = 0; reg < 4; ++reg) {
                const int rl = wm + i * 16 + quad * 4 + reg;
                const int R = vmode ? cl : rl;
                const int Cc = vmode ? rl : cl;
                const int idx = R * 128 + ((((Cc >> 3) ^ (R & 15)) << 3) | (Cc & 7));
                sm.C[idx] = f2bf(acc[i][j][reg] + bv);
            }
    }
    __syncthreads();

    const int rr = tid >> 1, half = tid & 1;
    u16* dst;
    if (vmode) {
        const int bb = rowBase >> 10, s0 = rowBase & 1023;
        dst = (u16*)g.Y + (size_t)bb * M1 + (size_t)(colBase + rr) * 1024 + s0 + half * 64;
    } else {
        dst = (u16*)g.Y + (size_t)(rowBase + rr) * 1024 + colBase + half * 64;
    }
#pragma unroll
    for (int k2 = 0; k2 < 8; ++k2) {
        const int chunk = half * 8 + k2;
        const int4 v = *(const int4*)(sm.C + rr * 128 + ((chunk ^ (rr & 15)) << 3));
        *(int4*)(dst + k2 * 8) = v;
    }
}

// ---------------------------------------------------------------------------
// Flash attention: exact R7 version (no setprio — R8's total regression may
// include it; revert to known-good). Paired q-tiles (qp, 15-qp), double-
// buffered K/V staging, softmax base-2, ctx in place over qw.
// ---------------------------------------------------------------------------
static __device__ __forceinline__ void attn_strip(
    const u16* __restrict__ Ks, const u16* __restrict__ Vs,
    u16* __restrict__ psw, const bf16x8* aq,
    float* m_run, float* l_run, f32x4* O,
    int w, int quad, int l16, bool diag)
{
    f32x4 s[4];
#pragma unroll
    for (int j = 0; j < 4; ++j) {
        const int r = j * 16 + l16;
        const bf16x8 b0 = ldfrag(Ks, ((r >> 3) << 6) | (quad << 3) | (r & 7));
        const bf16x8 b1 = ldfrag(Ks, ((r >> 3) << 6) | ((4 + quad) << 3) | (r & 7));
        f32x4 z = f32x4{0.f, 0.f, 0.f, 0.f};
        z = mfma16(aq[0], b0, z);
        s[j] = mfma16(aq[1], b1, z);
    }

    const float SC2 = 0.125f * 1.44269504089f;   // scale * log2(e)
    const int qrow0 = w * 16 + quad * 4;
#pragma unroll
    for (int j = 0; j < 4; ++j) {
        const int key = j * 16 + l16;
#pragma unroll
        for (int reg = 0; reg < 4; ++reg) {
            float v = s[j][reg] * SC2;
            if (diag && key > qrow0 + reg) v = -1e30f;
            s[j][reg] = v;
        }
    }

    float alpha[4];
#pragma unroll
    for (int reg = 0; reg < 4; ++reg) {
        float mx = fmaxf(fmaxf(s[0][reg], s[1][reg]), fmaxf(s[2][reg], s[3][reg]));
#pragma unroll
        for (int d = 1; d < 16; d <<= 1)
            mx = fmaxf(mx, __shfl_xor(mx, d));
        const float m_new = fmaxf(m_run[reg], mx);
        alpha[reg] = fexp2(m_run[reg] - m_new);
        float sm = 0.f;
#pragma unroll
        for (int j = 0; j < 4; ++j) {
            const float p = fexp2(s[j][reg] - m_new);
            s[j][reg] = p;
            sm += p;
        }
#pragma unroll
        for (int d = 1; d < 16; d <<= 1)
            sm += __shfl_xor(sm, d);
        l_run[reg] = l_run[reg] * alpha[reg] + sm;
        m_run[reg] = m_new;
    }

#pragma unroll
    for (int j = 0; j < 4; ++j)
#pragma unroll
        for (int reg = 0; reg < 4; ++reg)
            psw[(quad * 4 + reg) * 72 + j * 16 + l16] = f2bf(s[j][reg]);

#pragma unroll
    for (int j = 0; j < 4; ++j)
#pragma unroll
        for (int reg = 0; reg < 4; ++reg)
            O[j][reg] *= alpha[reg];

    bf16x8 ap[2];
#pragma unroll
    for (int kt = 0; kt < 2; ++kt)
        ap[kt] = *(const bf16x8*)((const char*)psw + (size_t)l16 * 144 + kt * 64 + quad * 16);
#pragma unroll
    for (int j = 0; j < 4; ++j) {
        const int r = j * 16 + l16;   // d row of V^T
        const bf16x8 b0 = ldfrag(Vs, ((r >> 3) << 6) | (quad << 3) | (r & 7));
        const bf16x8 b1 = ldfrag(Vs, ((r >> 3) << 6) | ((4 + quad) << 3) | (r & 7));
        O[j] = mfma16(ap[0], b0, O[j]);
        O[j] = mfma16(ap[1], b1, O[j]);
    }
}

__global__ __launch_bounds__(256) void attn_mfma(
    u16* __restrict__ qw, const u16* __restrict__ kw, const u16* __restrict__ vt)
{
    __shared__ __align__(16) u16 QA[64 * 64];
    __shared__ __align__(16) u16 QB[64 * 64];
    __shared__ __align__(16) u16 Ks[2][64 * 64];
    __shared__ __align__(16) u16 Vs[2][64 * 64];
    __shared__ __align__(16) u16 Ps[4][16 * 72];

    const int tid = threadIdx.x;
    const int lane = tid & 63, w = tid >> 6;
    const int quad = lane >> 4, l16 = lane & 15;
    const int qp = blockIdx.x, bh = blockIdx.y;
    const int b = bh >> 4, h = bh & 15;
    const int qtA = qp, qtB = 15 - qp;

    const u16* qgA = qw + (size_t)(b * 1024 + qtA * 64) * 1024 + h * 64;
    const u16* qgB = qw + (size_t)(b * 1024 + qtB * 64) * 1024 + h * 64;
    const u16* kg0 = kw + (size_t)(b * 1024) * 1024 + h * 64;
    const u16* vg0 = vt + (size_t)b * M1 + (size_t)(h * 64) * 1024;

    auto stageKV = [&](int buf, int kb) {
#pragma unroll
        for (int c = 0; c < 2; ++c) {
            const int l = c * 256 + tid;
            const int r = ((l >> 6) << 3) | (l & 7);
            const int kc = (l >> 3) & 7;
            g2lds16(kg0 + (size_t)(kb + r) * 1024 + kc * 8, (char*)Ks[buf] + (size_t)l * 16);
            g2lds16(vg0 + (size_t)r * 1024 + kb + kc * 8,   (char*)Vs[buf] + (size_t)l * 16);
        }
    };

#pragma unroll
    for (int c = 0; c < 2; ++c) {
        const int l = c * 256 + tid;
        const int r = ((l >> 6) << 3) | (l & 7);
        const int kc = (l >> 3) & 7;
        g2lds16(qgA + (size_t)r * 1024 + kc * 8, (char*)QA + (size_t)l * 16);
        g2lds16(qgB + (size_t)r * 1024 + kc * 8, (char*)QB + (size_t)l * 16);
    }
    stageKV(0, 0);
    __syncthreads();

    bf16x8 aqA[2], aqB[2];
    {
        const int r = w * 16 + l16;
#pragma unroll
        for (int kt = 0; kt < 2; ++kt) {
            aqA[kt] = ldfrag(QA, ((r >> 3) << 6) | ((kt * 4 + quad) << 3) | (r & 7));
            aqB[kt] = ldfrag(QB, ((r >> 3) << 6) | ((kt * 4 + quad) << 3) | (r & 7));
        }
    }

    f32x4 OA[4], OB[4];
    float mA[4], lA[4], mB[4], lB[4];
#pragma unroll
    for (int j = 0; j < 4; ++j) {
        OA[j] = f32x4{0.f, 0.f, 0.f, 0.f};
        OB[j] = f32x4{0.f, 0.f, 0.f, 0.f};
        mA[j] = -1e30f; lA[j] = 0.f;
        mB[j] = -1e30f; lB[j] = 0.f;
    }
    u16* psw = Ps[w];

    int cur = 0;
    for (int t = 0; t <= qtB; ++t) {
        if (t < qtB) stageKV(cur ^ 1, (t + 1) * 64);   // overlap with compute
        attn_strip(Ks[cur], Vs[cur], psw, aqB, mB, lB, OB, w, quad, l16, t == qtB);
        if (t <= qtA)
            attn_strip(Ks[cur], Vs[cur], psw, aqA, mA, lA, OA, w, quad, l16, t == qtA);
        __syncthreads();   // next buf resident; this buf free
        cur ^= 1;
    }

#pragma unroll
    for (int half = 0; half < 2; ++half) {
        const int qt = half ? qtB : qtA;
        const float* lr = half ? lB : lA;
        const f32x4* O = half ? OB : OA;
        u16* og = qw + (size_t)(b * 1024 + qt * 64 + w * 16 + quad * 4) * 1024 + h * 64;
#pragma unroll
        for (int reg = 0; reg < 4; ++reg) {
            const float inv = 1.f / lr[reg];
#pragma unroll
            for (int j = 0; j < 4; ++j)
                og[(size_t)reg * 1024 + j * 16 + l16] = f2bf(O[j][reg] * inv);
        }
    }
}

// ---------------------------------------------------------------------------
extern "C" void kernel_launch(void* const* d_in, const int* in_sizes, int n_in,
                              void* d_out, int out_size, void* d_ws, size_t ws_size,
                              hipStream_t stream)
{
    const void* query = d_in[0];
    const void* key   = d_in[1];
    const void* value = d_in[2];
    // d_in[3] = mask: exactly tril(ones) -> causal, not read
    const void* Wq = d_in[4];
    const void* bq = d_in[5];
    const void* Wk = d_in[6];
    const void* bk = d_in[7];
    const void* Wv = d_in[8];
    const void* bv = d_in[9];
    const void* Wo = d_in[10];
    const void* bo = d_in[11];

    // ws (u16 units): qw@0(4M1) kw@4 vt@8 wt_o@12 wt_q@13 wt_k@14 wt_v@15
    // flag@16M1. Total 32MB+4 (proven safe R4-R8).
    u16* qw   = (u16*)d_ws;
    u16* kw   = qw + 4 * M1;
    u16* vt   = qw + 8 * M1;
    u16* wt_o = qw + 12 * M1;
    u16* wt_q = qw + 13 * M1;
    u16* wt_k = qw + 14 * M1;
    u16* wt_v = qw + 15 * M1;
    int* flag = (int*)(qw + 16 * M1);

    sniff_kernel<<<1, 64, 0, stream>>>((const u16*)query, flag);

    T4 wT; wT.src[0] = Wq; wT.src[1] = Wk; wT.src[2] = Wv; wT.src[3] = Wo;
    wT.dst[0] = wt_q; wT.dst[1] = wt_k; wT.dst[2] = wt_v; wT.dst[3] = wt_o;
    transpose64<<<dim3(16, 16, 4), 256, 0, stream>>>(wT, flag, 1);

    G3 qkv;
    qkv.g[0] = G1{query, wt_q, bq, qw, 0};
    qkv.g[1] = G1{key,   wt_k, bk, kw, 0};
    qkv.g[2] = G1{value, wt_v, bv, vt, 1};   // V written pre-transposed
    gemm_mfma256<<<dim3(16, 4, 3), 512, 0, stream>>>(qkv, flag, 1);

    attn_mfma<<<dim3(8, 64), 256, 0, stream>>>(qw, kw, vt);

    G3 og;
    og.g[0] = G1{qw, wt_o, bo, d_out, 2};
    og.g[1] = og.g[0]; og.g[2] = og.g[0];
    gemm_mfma<<<dim3(32, 8, 1), 256, 0, stream>>>(og, flag, 0);
}